// Round 21
// baseline (351.983 us; speedup 1.0000x reference)
//
#include <hip/hip_runtime.h>
#include <hip/hip_bf16.h>

typedef float f32x4 __attribute__((ext_vector_type(4)));
typedef short short8 __attribute__((ext_vector_type(8)));
typedef unsigned int uint2v __attribute__((ext_vector_type(2)));

#define DI __device__ __forceinline__

DI unsigned short f2bf(float f) {
  unsigned int u = __float_as_uint(f);
  u += 0x7fffu + ((u >> 16) & 1u);
  return (unsigned short)(u >> 16);
}

DI float bf2f(unsigned short u) {
  union { unsigned int i; float f; } x;
  x.i = ((unsigned int)u) << 16;
  return x.f;
}

DI unsigned int packbf(float a, float b) {
  return (unsigned int)f2bf(a) | ((unsigned int)f2bf(b) << 16);
}

DI void gload16(const unsigned short* g, unsigned short* l) {
  __builtin_amdgcn_global_load_lds((const __attribute__((address_space(1))) void*)g,
                                   (__attribute__((address_space(3))) void*)l, 16, 0, 0);
}

// ---------------- elementwise f32 -> bf16 (NT source: read-once stream) ----------------
__global__ void cvt_bf16_kernel(const float* __restrict__ src,
                                unsigned short* __restrict__ dst, long n) {
  long i = ((long)blockIdx.x * blockDim.x + threadIdx.x) * 8;
  if (i >= n) return;
  f32x4 a = __builtin_nontemporal_load((const f32x4*)(src + i));
  f32x4 b = __builtin_nontemporal_load((const f32x4*)(src + i + 4));
  short8 v;
  v[0] = f2bf(a[0]); v[1] = f2bf(a[1]); v[2] = f2bf(a[2]); v[3] = f2bf(a[3]);
  v[4] = f2bf(b[0]); v[5] = f2bf(b[1]); v[6] = f2bf(b[2]); v[7] = f2bf(b[3]);
  *(short8*)(dst + i) = v;
}

// ---------------- tiled transpose + convert (f32 [R][C] -> bf16 [C][R]) ----------------
__global__ void transpose_cvt_kernel(const float* __restrict__ src,
                                     unsigned short* __restrict__ dst,
                                     int ldsrc, int lddst, long sBatch, long dBatch) {
  __shared__ float tile[32][33];
  const float* s = src + (long)blockIdx.z * sBatch;
  unsigned short* d = dst + (long)blockIdx.z * dBatch;
  int c0 = blockIdx.x * 32, r0 = blockIdx.y * 32;
  int tx = threadIdx.x, ty = threadIdx.y;
#pragma unroll
  for (int k = 0; k < 4; k++)
    tile[ty + 8 * k][tx] =
        __builtin_nontemporal_load(s + (long)(r0 + ty + 8 * k) * ldsrc + c0 + tx);
  __syncthreads();
#pragma unroll
  for (int k = 0; k < 4; k++)
    d[(long)(c0 + ty + 8 * k) * lddst + r0 + tx] = f2bf(tile[tx][ty + 8 * k]);
}

// ---------------- V transpose into blocked, granule-swizzled layout ----------------
// dst: VtC [b][kc=s>>5][256 d][32 kw], element kw stored at kw ^ (((d>>1)&3)<<3)
__global__ void transpose_v_kernel(const float* __restrict__ qkv,
                                   unsigned short* __restrict__ VtC) {
  __shared__ float tile[32][33];
  int b = blockIdx.z;
  int d0 = blockIdx.x * 32, s0 = blockIdx.y * 32;
  int tx = threadIdx.x, ty = threadIdx.y;
  const float* s = qkv + (long)b * 2048 * 2560 + 2304;
#pragma unroll
  for (int k = 0; k < 4; k++)
    tile[ty + 8 * k][tx] = s[(long)(s0 + ty + 8 * k) * 2560 + d0 + tx];
  __syncthreads();
  unsigned short* d = VtC + (long)b * 524288 + (long)(s0 >> 5) * 8192;
#pragma unroll
  for (int k = 0; k < 4; k++) {
    int dd = d0 + ty + 8 * k;
    d[dd * 32 + (tx ^ (((dd >> 1) & 3) << 3))] = f2bf(tile[tx][ty + 8 * k]);
  }
}

// ---------------- RoPE: one block per (b,s) row; cos/sin read ONCE per row ----------------
__global__ void rope_kernel(const float* __restrict__ qkv, const float* __restrict__ cs,
                            const float* __restrict__ sn, unsigned short* __restrict__ Qb,
                            unsigned short* __restrict__ Ksw) {
  int bs = blockIdx.x;     // b*2048 + s
  int d = threadIdx.x;     // 0..255
  long ci = (long)bs * 256 + d;
  float cv = cs[ci], sv = sn[ci];
  int b = bs >> 11, s2 = bs & 2047;
  const float* row = qkv + (long)bs * 2560;
  int off = (d < 128) ? 128 : -128;
  float sgn = (d < 128) ? -1.f : 1.f;
#pragma unroll
  for (int hp = 0; hp < 9; hp++) {
    float x = row[hp * 256 + d];
    float o = sgn * row[hp * 256 + d + off];
    unsigned short v = f2bf(x * cv + o * sv);
    if (hp < 8) {
      Qb[((long)(b * 8 + hp) * 2048 + s2) * 256 + d] = v;
    } else {
      Ksw[(long)bs * 256 + (d ^ ((bs & 7) << 3))] = v;
    }
  }
}

// ---------------- generic 128x128 MFMA GEMM: C = A @ Bt^T (XCD-swizzled grid) ----------------
template <bool AF32, bool CBF16, bool CNT>
__launch_bounds__(256)
__global__ void gemm_bt_kernel(const void* __restrict__ Av,
                               const unsigned short* __restrict__ Btg,
                               void* __restrict__ Cv,
                               int K, int lda, int ldb, int ldc,
                               int zShift, long aBatch, long bBatch, long cBatch, long cHead) {
  __shared__ unsigned short Asm_[128 * 32];
  __shared__ unsigned short Bsm_[128 * 32];
  int z = blockIdx.z;
  int zb = z >> zShift, zh = z - (zb << zShift);
  const unsigned short* Bt = Btg + (long)zb * bBatch;
  const unsigned short* A16 = (const unsigned short*)Av + (long)z * aBatch;
  const float* A32 = (const float*)Av + (long)z * aBatch;
  int nwg = gridDim.x * gridDim.y;
  int bid = blockIdx.y * gridDim.x + blockIdx.x;
  int qq = nwg >> 3;
  int swz = (bid & 7) * qq + (bid >> 3);
  int m0 = (swz / gridDim.x) * 128, n0 = (swz % gridDim.x) * 128;
  int tid = threadIdx.x, w = tid >> 6, lane = tid & 63, c = lane & 15, t = lane >> 4;
  int wm = w >> 1, wn = w & 1;
  f32x4 zero4 = {0.f, 0.f, 0.f, 0.f};
  f32x4 acc[4][4];
#pragma unroll
  for (int i = 0; i < 4; i++)
#pragma unroll
    for (int j = 0; j < 4; j++) acc[i][j] = zero4;

  for (int kt = 0; kt < K; kt += 32) {
    if constexpr (!AF32) {
#pragma unroll
      for (int jj = 0; jj < 2; jj++) {
        int slot = (w * 2 + jj) * 64 + lane;
        int r = slot >> 2, g = slot & 3;
        int gs = g ^ ((r >> 1) & 3);
        gload16(A16 + (long)(m0 + r) * lda + kt + gs * 8, Asm_ + slot * 8);
      }
    } else {
#pragma unroll
      for (int jj = 0; jj < 2; jj++) {
        int slot = jj * 256 + tid;
        int r = slot >> 2, g = slot & 3;
        int gs = g ^ ((r >> 1) & 3);
        const float* p = A32 + (long)(m0 + r) * lda + kt + gs * 8;
        float4 x = *(const float4*)p;
        float4 y = *(const float4*)(p + 4);
        short8 v;
        v[0] = f2bf(x.x); v[1] = f2bf(x.y); v[2] = f2bf(x.z); v[3] = f2bf(x.w);
        v[4] = f2bf(y.x); v[5] = f2bf(y.y); v[6] = f2bf(y.z); v[7] = f2bf(y.w);
        *(short8*)(Asm_ + slot * 8) = v;
      }
    }
#pragma unroll
    for (int jj = 0; jj < 2; jj++) {
      int slot = (w * 2 + jj) * 64 + lane;
      int r = slot >> 2, g = slot & 3;
      int gs = g ^ ((r >> 1) & 3);
      gload16(Bt + (long)(n0 + r) * ldb + kt + gs * 8, Bsm_ + slot * 8);
    }
    __syncthreads();
    short8 af[4], bfg[4];
#pragma unroll
    for (int mi = 0; mi < 4; mi++) {
      int r = wm * 64 + mi * 16 + c;
      af[mi] = *(const short8*)(Asm_ + r * 32 + ((t ^ ((r >> 1) & 3)) * 8));
    }
#pragma unroll
    for (int ni = 0; ni < 4; ni++) {
      int r = wn * 64 + ni * 16 + c;
      bfg[ni] = *(const short8*)(Bsm_ + r * 32 + ((t ^ ((r >> 1) & 3)) * 8));
    }
#pragma unroll
    for (int mi = 0; mi < 4; mi++)
#pragma unroll
      for (int ni = 0; ni < 4; ni++)
        acc[mi][ni] = __builtin_amdgcn_mfma_f32_16x16x32_bf16(af[mi], bfg[ni], acc[mi][ni], 0, 0, 0);
    __syncthreads();
  }
  long cOff = (long)zb * cBatch + zh * cHead;
#pragma unroll
  for (int mi = 0; mi < 4; mi++) {
#pragma unroll
    for (int j = 0; j < 4; j++) {
      int row = m0 + wm * 64 + mi * 16 + t * 4 + j;
#pragma unroll
      for (int ni = 0; ni < 4; ni++) {
        int col = n0 + wn * 64 + ni * 16 + c;
        float v = acc[mi][ni][j];
        long idx = cOff + (long)row * ldc + col;
        if constexpr (CBF16) {
          ((unsigned short*)Cv)[idx] = f2bf(v);
        } else if constexpr (CNT) {
          __builtin_nontemporal_store(v, (float*)Cv + idx);
        } else {
          ((float*)Cv)[idx] = v;
        }
      }
    }
  }
}

// ---------------- fused attention: QK^T + softmax + attnW store + PV ----------------
// grid 512 (XCD-swizzled), block 256 thr = 4 waves = 2 q-groups(32q) x 2 roles.
// Wave (g,h): QK/exp on its 32 q (two 16-q subtiles, SHARED K fragment reads)
// over k-rows [16h,16h+16); PV on d-cols [128h,128h+128) for both subtiles
// (SHARED V fragment reads). K/V LDS amplification halved vs 16q/wave.
// Pass 2 pipelined by one chunk; counted vmcnt; mask reg-dbuf; full-line
// cooperative attnW stores (values = f32(bf16(p))); NT output stores.
#define KC 32
__launch_bounds__(256, 2)
__global__ void attn_fused_kernel(const unsigned short* __restrict__ Qb,
                                  const unsigned short* __restrict__ Ksw,
                                  const unsigned short* __restrict__ VtC,
                                  const float* __restrict__ mask,
                                  float* __restrict__ attnW,
                                  unsigned short* __restrict__ attnO) {
  __shared__ unsigned short Ksm[2][KC * 256];      // 2 x 16KB
  __shared__ unsigned short Vsm[2][256 * KC];      // 2 x 16KB
  __shared__ unsigned short Pt[2][2][2][16 * 32];  // [dbuf][qgroup][sub] 8KB
  __shared__ float red[4][32];
  const int id = blockIdx.x;
  const int sw = (id & 7) * 64 + (id >> 3);
  const int qblk = sw & 31, bh = sw >> 5;
  const int b = bh >> 3;
  const int tid = threadIdx.x, w = tid >> 6, lane = tid & 63;
  const int c = lane & 15, t = lane >> 4;
  const int g = w & 1, h = w >> 1;
  const int qa = qblk * 64 + g * 32;   // wave's 32 q rows (two 16-q subtiles)
  const int kh = 16 * h;               // wave's k-row offset within each chunk
  const float scale = 0.0625f;

  // Q fragments for both subtiles (B-operand: col=c -> qa+c and qa+16+c)
  short8 qfa[8], qfb[8];
  {
    const unsigned short* Qra = Qb + ((long)bh * 2048 + qa + c) * 256 + t * 8;
    const unsigned short* Qrb = Qra + 16 * 256;
#pragma unroll
    for (int ks = 0; ks < 8; ks++) {
      qfa[ks] = *(const short8*)(Qra + ks * 32);
      qfb[ks] = *(const short8*)(Qrb + ks * 32);
    }
  }

  const unsigned short* Kg = Ksw + (long)b * 524288;
  const unsigned short* Vg = VtC + (long)b * 524288;
  const float* mra = mask + (long)b * 4194304 + (long)(qa + c) * 2048 + kh + t * 4;
  const float* mrb = mra + 16 * 2048;

  float lp0 = 0.f, lp1 = 0.f;

  // ---- pass 1: partial sums of exp(s) over this wave's k-half rows ----
#pragma unroll
  for (int i = 0; i < 4; i++) {
    int slot = i * 256 + tid;
    gload16(Kg + slot * 8, Ksm[0] + slot * 8);
  }
  f32x4 mva = *(const f32x4*)(mra);
  f32x4 mvb = *(const f32x4*)(mrb);
  for (int kc = 0; kc < 64; kc++) {
    int cur = kc & 1;
    asm volatile("s_barrier" ::: "memory");
    f32x4 mna, mnb;
    if (kc < 63) {
      const unsigned short* src = Kg + (long)(kc + 1) * 8192;
#pragma unroll
      for (int i = 0; i < 4; i++) {
        int slot = i * 256 + tid;
        gload16(src + slot * 8, Ksm[cur ^ 1] + slot * 8);
      }
      mna = *(const f32x4*)(mra + (kc + 1) * 32);
      mnb = *(const f32x4*)(mrb + (kc + 1) * 32);
      asm volatile("s_waitcnt vmcnt(6)" ::: "memory");  // prev K retired
    } else {
      asm volatile("s_waitcnt vmcnt(0)" ::: "memory");
    }
    __builtin_amdgcn_sched_barrier(0);
    f32x4 a0 = {0.f, 0.f, 0.f, 0.f}, a1 = a0;
    __builtin_amdgcn_s_setprio(1);
#pragma unroll
    for (int ks = 0; ks < 8; ks++) {
      int g0 = ((ks * 4 + t) ^ (c & 7)) * 8;
      short8 kf = *(const short8*)(Ksm[cur] + (kh + c) * 256 + g0);
      a0 = __builtin_amdgcn_mfma_f32_16x16x32_bf16(kf, qfa[ks], a0, 0, 0, 0);
      a1 = __builtin_amdgcn_mfma_f32_16x16x32_bf16(kf, qfb[ks], a1, 0, 0, 0);
    }
    __builtin_amdgcn_s_setprio(0);
#pragma unroll
    for (int j = 0; j < 4; j++) {
      lp0 += __expf(a0[j] * scale + mva[j]);
      lp1 += __expf(a1[j] * scale + mvb[j]);
    }
    mva = mna; mvb = mnb;
  }
  lp0 += __shfl_xor(lp0, 16); lp0 += __shfl_xor(lp0, 32);
  lp1 += __shfl_xor(lp1, 16); lp1 += __shfl_xor(lp1, 32);
  if (t == 0) { red[w][c] = lp0; red[w][16 + c] = lp1; }
  __syncthreads();
  float ri0 = 1.0f / (red[g][c] + red[g + 2][c]);
  float ri1 = 1.0f / (red[g][16 + c] + red[g + 2][16 + c]);

  // ---- pass 2: one barrier/iter; PV and attnW-store lag QK by one chunk ----
  const int psw = ((c >> 1) & 3) << 3;   // bank-bijective granule swizzle (c bits [2:1])
  // cooperative attnW store indexing: 256 threads x 2 lines -> 64 rows x 8 quarters
  float* awB = attnW + (long)bh * 4194304 + (long)(qblk * 64) * 2048;
  f32x4 accO[2][8];
#pragma unroll
  for (int i = 0; i < 2; i++)
#pragma unroll
    for (int j = 0; j < 8; j++) accO[i][j] = (f32x4){0.f, 0.f, 0.f, 0.f};

#pragma unroll
  for (int i = 0; i < 4; i++) {
    int slot = i * 256 + tid;
    gload16(Kg + slot * 8, Ksm[0] + slot * 8);
  }
  mva = *(const f32x4*)(mra);
  mvb = *(const f32x4*)(mrb);
  for (int kc = 0; kc < 64; kc++) {
    int cur = kc & 1;
    asm volatile("s_barrier" ::: "memory");
    f32x4 mna, mnb;
    if (kc < 63) {
      const unsigned short* ksrc = Kg + (long)(kc + 1) * 8192;
      const unsigned short* vsrc = Vg + (long)kc * 8192;   // V[kc] consumed NEXT iter
#pragma unroll
      for (int i = 0; i < 4; i++) {
        int slot = i * 256 + tid;
        gload16(ksrc + slot * 8, Ksm[cur ^ 1] + slot * 8);
        gload16(vsrc + slot * 8, Vsm[cur] + slot * 8);
      }
      mna = *(const f32x4*)(mra + (kc + 1) * 32);
      mnb = *(const f32x4*)(mrb + (kc + 1) * 32);
      asm volatile("s_waitcnt vmcnt(10)" ::: "memory");  // prev iter's K+V retired
    } else {
      const unsigned short* vsrc = Vg + (long)kc * 8192;   // V[63]
#pragma unroll
      for (int i = 0; i < 4; i++) {
        int slot = i * 256 + tid;
        gload16(vsrc + slot * 8, Vsm[cur] + slot * 8);
      }
      asm volatile("s_waitcnt vmcnt(4)" ::: "memory");  // K[63] + V[62] retired
    }
    __builtin_amdgcn_sched_barrier(0);
    f32x4 a0 = {0.f, 0.f, 0.f, 0.f}, a1 = a0;
    __builtin_amdgcn_s_setprio(1);
#pragma unroll
    for (int ks = 0; ks < 8; ks++) {
      int g0 = ((ks * 4 + t) ^ (c & 7)) * 8;
      short8 kf = *(const short8*)(Ksm[cur] + (kh + c) * 256 + g0);
      a0 = __builtin_amdgcn_mfma_f32_16x16x32_bf16(kf, qfa[ks], a0, 0, 0, 0);
      a1 = __builtin_amdgcn_mfma_f32_16x16x32_bf16(kf, qfb[ks], a1, 0, 0, 0);
    }
    __builtin_amdgcn_s_setprio(0);
    f32x4 p0, p1;
#pragma unroll
    for (int j = 0; j < 4; j++) {
      p0[j] = __expf(a0[j] * scale + mva[j]) * ri0;
      p1[j] = __expf(a1[j] * scale + mvb[j]) * ri1;
    }
    mva = mna; mvb = mnb;
    // P[kc] -> bf16 into Pt[cur][g][sub] (element k stored at k ^ psw)
    uint2v pw0, pw1;
    pw0[0] = packbf(p0[0], p0[1]); pw0[1] = packbf(p0[2], p0[3]);
    pw1[0] = packbf(p1[0], p1[1]); pw1[1] = packbf(p1[2], p1[3]);
    *(uint2v*)(&Pt[cur][g][0][0] + c * 32 + ((kh + t * 4) ^ psw)) = pw0;
    *(uint2v*)(&Pt[cur][g][1][0] + c * 32 + ((kh + t * 4) ^ psw)) = pw1;
    if (kc >= 1) {
      // attnW store of chunk kc-1 from Pt[cur^1]: 2 full 128B lines per thread
#pragma unroll
      for (int li = 0; li < 2; li++) {
        int slot2 = li * 256 + tid;          // 0..511
        int srow = slot2 >> 3, sqk = slot2 & 7;
        int sg = srow >> 5, ssub = (srow >> 4) & 1, sc2 = srow & 15;
        int spsw2 = ((sc2 >> 1) & 3) << 3;
        uint2v pu = *(const uint2v*)(&Pt[cur ^ 1][sg][ssub][0] + sc2 * 32 +
                                     ((sqk * 4) ^ spsw2));
        f32x4 aw;
        aw[0] = bf2f((unsigned short)(pu[0] & 0xffff));
        aw[1] = bf2f((unsigned short)(pu[0] >> 16));
        aw[2] = bf2f((unsigned short)(pu[1] & 0xffff));
        aw[3] = bf2f((unsigned short)(pu[1] >> 16));
        __builtin_nontemporal_store(
            aw, (f32x4*)(awB + (long)srow * 2048 + (kc - 1) * 32 + sqk * 4));
      }
      // PV(kc-1): A = P rows from Pt[cur^1] (both subtiles), B = shared V frags
      short8 pa0 = *(const short8*)(&Pt[cur ^ 1][g][0][0] + c * 32 + ((t * 8) ^ psw));
      short8 pa1 = *(const short8*)(&Pt[cur ^ 1][g][1][0] + c * 32 + ((t * 8) ^ psw));
      __builtin_amdgcn_s_setprio(1);
#pragma unroll
      for (int di = 0; di < 8; di++) {
        int d = (8 * h + di) * 16 + c;
        short8 vf = *(const short8*)(Vsm[cur ^ 1] + d * 32 + ((t * 8) ^ psw));
        accO[0][di] = __builtin_amdgcn_mfma_f32_16x16x32_bf16(pa0, vf, accO[0][di], 0, 0, 0);
        accO[1][di] = __builtin_amdgcn_mfma_f32_16x16x32_bf16(pa1, vf, accO[1][di], 0, 0, 0);
      }
      __builtin_amdgcn_s_setprio(0);
    }
    // publish Pt[cur] writes before the next top barrier
    asm volatile("s_waitcnt lgkmcnt(0)" ::: "memory");
  }
  // ---- epilogue: attnW chunk 63 + PV(63) from Pt[1] + Vsm[1] ----
  asm volatile("s_waitcnt vmcnt(0)" ::: "memory");   // V[63] landed
  __builtin_amdgcn_s_barrier();                       // Pt[1] published
  __builtin_amdgcn_sched_barrier(0);
  {
#pragma unroll
    for (int li = 0; li < 2; li++) {
      int slot2 = li * 256 + tid;
      int srow = slot2 >> 3, sqk = slot2 & 7;
      int sg = srow >> 5, ssub = (srow >> 4) & 1, sc2 = srow & 15;
      int spsw2 = ((sc2 >> 1) & 3) << 3;
      uint2v pu = *(const uint2v*)(&Pt[1][sg][ssub][0] + sc2 * 32 + ((sqk * 4) ^ spsw2));
      f32x4 aw;
      aw[0] = bf2f((unsigned short)(pu[0] & 0xffff));
      aw[1] = bf2f((unsigned short)(pu[0] >> 16));
      aw[2] = bf2f((unsigned short)(pu[1] & 0xffff));
      aw[3] = bf2f((unsigned short)(pu[1] >> 16));
      __builtin_nontemporal_store(
          aw, (f32x4*)(awB + (long)srow * 2048 + 63 * 32 + sqk * 4));
    }
    short8 pa0 = *(const short8*)(&Pt[1][g][0][0] + c * 32 + ((t * 8) ^ psw));
    short8 pa1 = *(const short8*)(&Pt[1][g][1][0] + c * 32 + ((t * 8) ^ psw));
#pragma unroll
    for (int di = 0; di < 8; di++) {
      int d = (8 * h + di) * 16 + c;
      short8 vf = *(const short8*)(Vsm[1] + d * 32 + ((t * 8) ^ psw));
      accO[0][di] = __builtin_amdgcn_mfma_f32_16x16x32_bf16(pa0, vf, accO[0][di], 0, 0, 0);
      accO[1][di] = __builtin_amdgcn_mfma_f32_16x16x32_bf16(pa1, vf, accO[1][di], 0, 0, 0);
    }
  }
  // attnO epilogue: rows qa+sub*16+t*4+j, col = h*128 + di*16 + c (within head)
  long ob0 = ((long)b * 2048 + qa + t * 4) * 2048 + (bh & 7) * 256 + h * 128 + c;
  long ob1 = ob0 + 16 * 2048;
#pragma unroll
  for (int di = 0; di < 8; di++)
#pragma unroll
    for (int j = 0; j < 4; j++) {
      __builtin_nontemporal_store(f2bf(accO[0][di][j]),
                                  attnO + ob0 + (long)j * 2048 + di * 16);
      __builtin_nontemporal_store(f2bf(accO[1][di][j]),
                                  attnO + ob1 + (long)j * 2048 + di * 16);
    }
}

extern "C" void kernel_launch(void* const* d_in, const int* in_sizes, int n_in,
                              void* d_out, int out_size, void* d_ws, size_t ws_size,
                              hipStream_t stream) {
  const float* hidden = (const float*)d_in[0];
  const float* mask = (const float*)d_in[1];
  const float* cosb = (const float*)d_in[2];
  const float* sinb = (const float*)d_in[3];
  const float* Wq = (const float*)d_in[4];
  const float* Wk = (const float*)d_in[5];
  const float* Wv = (const float*)d_in[6];
  const float* Wo = (const float*)d_in[7];
  float* out = (float*)d_out;
  float* attnW = out + 8388608;  // attn_weights [2][8][2048][2048] f32

  char* ws = (char*)d_ws;
  unsigned short* hidB  = (unsigned short*)(ws + 0);          // [4096][2048] bf16
  unsigned short* WqkvT = (unsigned short*)(ws + 16777216);   // [2560][2048] bf16
  unsigned short* WoT   = (unsigned short*)(ws + 27262976);   // [2048][2048] bf16
  float*          qkv   = (float*)(ws + 35651584);            // [4096][2560] f32
  unsigned short* Qb    = (unsigned short*)(ws + 77594624);   // [16][2048][256] bf16
  unsigned short* Ksw   = (unsigned short*)(ws + 94371840);   // [2][2048][256] bf16 (swizzled)
  unsigned short* VtC   = (unsigned short*)(ws + 96468992);   // [2][64][256][32] bf16 (blocked)
  unsigned short* attnO = (unsigned short*)(ws + 98566144);   // [4096][2048] bf16

  // 1) hidden -> bf16
  cvt_bf16_kernel<<<4096, 256, 0, stream>>>(hidden, hidB, 8388608L);
  // 2) pack transposed weights (bf16)
  transpose_cvt_kernel<<<dim3(64, 64, 1), dim3(32, 8), 0, stream>>>(Wq, WqkvT, 2048, 2048, 0, 0);
  transpose_cvt_kernel<<<dim3(8, 64, 1), dim3(32, 8), 0, stream>>>(Wk, WqkvT + (long)2048 * 2048, 256, 2048, 0, 0);
  transpose_cvt_kernel<<<dim3(8, 64, 1), dim3(32, 8), 0, stream>>>(Wv, WqkvT + (long)2304 * 2048, 256, 2048, 0, 0);
  transpose_cvt_kernel<<<dim3(64, 64, 1), dim3(32, 8), 0, stream>>>(Wo, WoT, 2048, 2048, 0, 0);
  // 3) QKV projection: [4096][2560] f32
  gemm_bt_kernel<false, false, false><<<dim3(20, 32, 1), 256, 0, stream>>>(
      hidB, WqkvT, qkv, 2048, 2048, 2048, 2560, 0, 0, 0, 0, 0);
  // 4) RoPE -> Q bf16 linear, K bf16 swizzled (cos/sin read once per row)
  rope_kernel<<<4096, 256, 0, stream>>>(qkv, cosb, sinb, Qb, Ksw);
  // 5) V -> blocked transposed bf16
  transpose_v_kernel<<<dim3(8, 64, 2), dim3(32, 8), 0, stream>>>(qkv, VtC);
  // 6) fused attention: attnW (d_out) + attnO  (mask read directly as f32)
  attn_fused_kernel<<<512, 256, 0, stream>>>(Qb, Ksw, VtC, mask, attnW, attnO);
  // 7) output projection -> d_out (non-temporal C store: write-once stream)
  gemm_bt_kernel<false, false, true><<<dim3(16, 32, 1), 256, 0, stream>>>(
      attnO, WoT, out, 2048, 2048, 2048, 2048, 0, 0, 0, 0, 0);
}

// Round 22
// 348.356 us; speedup vs baseline: 1.0104x; 1.0104x over previous
//
#include <hip/hip_runtime.h>
#include <hip/hip_bf16.h>

typedef float f32x4 __attribute__((ext_vector_type(4)));
typedef short short8 __attribute__((ext_vector_type(8)));
typedef unsigned int uint2v __attribute__((ext_vector_type(2)));

#define DI __device__ __forceinline__

DI unsigned short f2bf(float f) {
  unsigned int u = __float_as_uint(f);
  u += 0x7fffu + ((u >> 16) & 1u);
  return (unsigned short)(u >> 16);
}

DI float bf2f(unsigned short u) {
  union { unsigned int i; float f; } x;
  x.i = ((unsigned int)u) << 16;
  return x.f;
}

DI unsigned int packbf(float a, float b) {
  return (unsigned int)f2bf(a) | ((unsigned int)f2bf(b) << 16);
}

DI void gload16(const unsigned short* g, unsigned short* l) {
  __builtin_amdgcn_global_load_lds((const __attribute__((address_space(1))) void*)g,
                                   (__attribute__((address_space(3))) void*)l, 16, 0, 0);
}

// ---------------- elementwise f32 -> bf16 (NT source: read-once stream) ----------------
__global__ void cvt_bf16_kernel(const float* __restrict__ src,
                                unsigned short* __restrict__ dst, long n) {
  long i = ((long)blockIdx.x * blockDim.x + threadIdx.x) * 8;
  if (i >= n) return;
  f32x4 a = __builtin_nontemporal_load((const f32x4*)(src + i));
  f32x4 b = __builtin_nontemporal_load((const f32x4*)(src + i + 4));
  short8 v;
  v[0] = f2bf(a[0]); v[1] = f2bf(a[1]); v[2] = f2bf(a[2]); v[3] = f2bf(a[3]);
  v[4] = f2bf(b[0]); v[5] = f2bf(b[1]); v[6] = f2bf(b[2]); v[7] = f2bf(b[3]);
  *(short8*)(dst + i) = v;
}

// ---------------- tiled transpose + convert (f32 [R][C] -> bf16 [C][R]) ----------------
__global__ void transpose_cvt_kernel(const float* __restrict__ src,
                                     unsigned short* __restrict__ dst,
                                     int ldsrc, int lddst, long sBatch, long dBatch) {
  __shared__ float tile[32][33];
  const float* s = src + (long)blockIdx.z * sBatch;
  unsigned short* d = dst + (long)blockIdx.z * dBatch;
  int c0 = blockIdx.x * 32, r0 = blockIdx.y * 32;
  int tx = threadIdx.x, ty = threadIdx.y;
#pragma unroll
  for (int k = 0; k < 4; k++)
    tile[ty + 8 * k][tx] =
        __builtin_nontemporal_load(s + (long)(r0 + ty + 8 * k) * ldsrc + c0 + tx);
  __syncthreads();
#pragma unroll
  for (int k = 0; k < 4; k++)
    d[(long)(c0 + ty + 8 * k) * lddst + r0 + tx] = f2bf(tile[tx][ty + 8 * k]);
}

// ---------------- V transpose into blocked, granule-swizzled layout ----------------
// dst: VtC [b][kc=s>>5][256 d][32 kw], element kw stored at kw ^ (((d>>1)&3)<<3)
__global__ void transpose_v_kernel(const float* __restrict__ qkv,
                                   unsigned short* __restrict__ VtC) {
  __shared__ float tile[32][33];
  int b = blockIdx.z;
  int d0 = blockIdx.x * 32, s0 = blockIdx.y * 32;
  int tx = threadIdx.x, ty = threadIdx.y;
  const float* s = qkv + (long)b * 2048 * 2560 + 2304;
#pragma unroll
  for (int k = 0; k < 4; k++)
    tile[ty + 8 * k][tx] = s[(long)(s0 + ty + 8 * k) * 2560 + d0 + tx];
  __syncthreads();
  unsigned short* d = VtC + (long)b * 524288 + (long)(s0 >> 5) * 8192;
#pragma unroll
  for (int k = 0; k < 4; k++) {
    int dd = d0 + ty + 8 * k;
    d[dd * 32 + (tx ^ (((dd >> 1) & 3) << 3))] = f2bf(tile[tx][ty + 8 * k]);
  }
}

// ---------------- RoPE: one block per (b,s) row; cos/sin read ONCE per row ----------------
__global__ void rope_kernel(const float* __restrict__ qkv, const float* __restrict__ cs,
                            const float* __restrict__ sn, unsigned short* __restrict__ Qb,
                            unsigned short* __restrict__ Ksw) {
  int bs = blockIdx.x;     // b*2048 + s
  int d = threadIdx.x;     // 0..255
  long ci = (long)bs * 256 + d;
  float cv = cs[ci], sv = sn[ci];
  int b = bs >> 11, s2 = bs & 2047;
  const float* row = qkv + (long)bs * 2560;
  int off = (d < 128) ? 128 : -128;
  float sgn = (d < 128) ? -1.f : 1.f;
#pragma unroll
  for (int hp = 0; hp < 9; hp++) {
    float x = row[hp * 256 + d];
    float o = sgn * row[hp * 256 + d + off];
    unsigned short v = f2bf(x * cv + o * sv);
    if (hp < 8) {
      Qb[((long)(b * 8 + hp) * 2048 + s2) * 256 + d] = v;
    } else {
      Ksw[(long)bs * 256 + (d ^ ((bs & 7) << 3))] = v;
    }
  }
}

// ---------------- generic 128x128 MFMA GEMM: C = A @ Bt^T (XCD-swizzled grid) ----------------
template <bool AF32, bool CBF16, bool CNT>
__launch_bounds__(256)
__global__ void gemm_bt_kernel(const void* __restrict__ Av,
                               const unsigned short* __restrict__ Btg,
                               void* __restrict__ Cv,
                               int K, int lda, int ldb, int ldc,
                               int zShift, long aBatch, long bBatch, long cBatch, long cHead) {
  __shared__ unsigned short Asm_[128 * 32];
  __shared__ unsigned short Bsm_[128 * 32];
  int z = blockIdx.z;
  int zb = z >> zShift, zh = z - (zb << zShift);
  const unsigned short* Bt = Btg + (long)zb * bBatch;
  const unsigned short* A16 = (const unsigned short*)Av + (long)z * aBatch;
  const float* A32 = (const float*)Av + (long)z * aBatch;
  int nwg = gridDim.x * gridDim.y;
  int bid = blockIdx.y * gridDim.x + blockIdx.x;
  int qq = nwg >> 3;
  int swz = (bid & 7) * qq + (bid >> 3);
  int m0 = (swz / gridDim.x) * 128, n0 = (swz % gridDim.x) * 128;
  int tid = threadIdx.x, w = tid >> 6, lane = tid & 63, c = lane & 15, t = lane >> 4;
  int wm = w >> 1, wn = w & 1;
  f32x4 zero4 = {0.f, 0.f, 0.f, 0.f};
  f32x4 acc[4][4];
#pragma unroll
  for (int i = 0; i < 4; i++)
#pragma unroll
    for (int j = 0; j < 4; j++) acc[i][j] = zero4;

  for (int kt = 0; kt < K; kt += 32) {
    if constexpr (!AF32) {
#pragma unroll
      for (int jj = 0; jj < 2; jj++) {
        int slot = (w * 2 + jj) * 64 + lane;
        int r = slot >> 2, g = slot & 3;
        int gs = g ^ ((r >> 1) & 3);
        gload16(A16 + (long)(m0 + r) * lda + kt + gs * 8, Asm_ + slot * 8);
      }
    } else {
#pragma unroll
      for (int jj = 0; jj < 2; jj++) {
        int slot = jj * 256 + tid;
        int r = slot >> 2, g = slot & 3;
        int gs = g ^ ((r >> 1) & 3);
        const float* p = A32 + (long)(m0 + r) * lda + kt + gs * 8;
        float4 x = *(const float4*)p;
        float4 y = *(const float4*)(p + 4);
        short8 v;
        v[0] = f2bf(x.x); v[1] = f2bf(x.y); v[2] = f2bf(x.z); v[3] = f2bf(x.w);
        v[4] = f2bf(y.x); v[5] = f2bf(y.y); v[6] = f2bf(y.z); v[7] = f2bf(y.w);
        *(short8*)(Asm_ + slot * 8) = v;
      }
    }
#pragma unroll
    for (int jj = 0; jj < 2; jj++) {
      int slot = (w * 2 + jj) * 64 + lane;
      int r = slot >> 2, g = slot & 3;
      int gs = g ^ ((r >> 1) & 3);
      gload16(Bt + (long)(n0 + r) * ldb + kt + gs * 8, Bsm_ + slot * 8);
    }
    __syncthreads();
    short8 af[4], bfg[4];
#pragma unroll
    for (int mi = 0; mi < 4; mi++) {
      int r = wm * 64 + mi * 16 + c;
      af[mi] = *(const short8*)(Asm_ + r * 32 + ((t ^ ((r >> 1) & 3)) * 8));
    }
#pragma unroll
    for (int ni = 0; ni < 4; ni++) {
      int r = wn * 64 + ni * 16 + c;
      bfg[ni] = *(const short8*)(Bsm_ + r * 32 + ((t ^ ((r >> 1) & 3)) * 8));
    }
#pragma unroll
    for (int mi = 0; mi < 4; mi++)
#pragma unroll
      for (int ni = 0; ni < 4; ni++)
        acc[mi][ni] = __builtin_amdgcn_mfma_f32_16x16x32_bf16(af[mi], bfg[ni], acc[mi][ni], 0, 0, 0);
    __syncthreads();
  }
  long cOff = (long)zb * cBatch + zh * cHead;
#pragma unroll
  for (int mi = 0; mi < 4; mi++) {
#pragma unroll
    for (int j = 0; j < 4; j++) {
      int row = m0 + wm * 64 + mi * 16 + t * 4 + j;
#pragma unroll
      for (int ni = 0; ni < 4; ni++) {
        int col = n0 + wn * 64 + ni * 16 + c;
        float v = acc[mi][ni][j];
        long idx = cOff + (long)row * ldc + col;
        if constexpr (CBF16) {
          ((unsigned short*)Cv)[idx] = f2bf(v);
        } else if constexpr (CNT) {
          __builtin_nontemporal_store(v, (float*)Cv + idx);
        } else {
          ((float*)Cv)[idx] = v;
        }
      }
    }
  }
}

// ---------------- fused attention: QK^T + softmax + attnW store + PV ----------------
// grid 512 (XCD-swizzled), block 512 thr = 8 waves = 4 q-subtiles x 2 roles.
// Pass 2 pipelined by one chunk. attnW is emitted from the Pt LDS tile as FULL
// 128B lines (8 lanes per row-chunk, cooperative across the block) -> no
// partial-line RMW; values = f32(bf16(p)), identical to the P used for PV.
#define KC 32
__launch_bounds__(512, 4)
__global__ void attn_fused_kernel(const unsigned short* __restrict__ Qb,
                                  const unsigned short* __restrict__ Ksw,
                                  const unsigned short* __restrict__ VtC,
                                  const float* __restrict__ mask,
                                  float* __restrict__ attnW,
                                  unsigned short* __restrict__ attnO) {
  __shared__ unsigned short Ksm[2][KC * 256];   // 2 x 16KB
  __shared__ unsigned short Vsm[2][256 * KC];   // 2 x 16KB
  __shared__ unsigned short Pt[2][4][16 * 32];  // double-buffered P tiles, 8KB
  __shared__ float red[8][16];
  const int id = blockIdx.x;
  const int sw = (id & 7) * 64 + (id >> 3);
  const int qblk = sw & 31, bh = sw >> 5;
  const int b = bh >> 3;
  const int tid = threadIdx.x, w = tid >> 6, lane = tid & 63;
  const int c = lane & 15, t = lane >> 4;
  const int s = w & 3, h = w >> 2;
  const int q0 = qblk * 64 + s * 16;   // wave's 16 q rows
  const int kh = 16 * h;               // wave's k-row offset within each chunk
  const float scale = 0.0625f;

  // Q fragments (B-operand: col=c -> q0+c)
  short8 qf[8];
  {
    const unsigned short* Qrow = Qb + ((long)bh * 2048 + q0 + c) * 256 + t * 8;
#pragma unroll
    for (int ks = 0; ks < 8; ks++) qf[ks] = *(const short8*)(Qrow + ks * 32);
  }

  const unsigned short* Kg = Ksw + (long)b * 524288;
  const unsigned short* Vg = VtC + (long)b * 524288;
  const float* mrow = mask + (long)b * 4194304 + (long)(q0 + c) * 2048 + kh + t * 4;

  float lp = 0.f;

  // ---- pass 1: partial sum of exp(s) over this wave's k-half rows ----
#pragma unroll
  for (int i = 0; i < 2; i++) {
    int slot = i * 512 + tid;
    gload16(Kg + slot * 8, Ksm[0] + slot * 8);
  }
  f32x4 mv = *(const f32x4*)(mrow);   // prefetch mask for kc=0
  for (int kc = 0; kc < 64; kc++) {
    int cur = kc & 1;
    asm volatile("s_barrier" ::: "memory");
    f32x4 mvn;
    if (kc < 63) {
      const unsigned short* src = Kg + (long)(kc + 1) * 8192;
#pragma unroll
      for (int i = 0; i < 2; i++) {
        int slot = i * 512 + tid;
        gload16(src + slot * 8, Ksm[cur ^ 1] + slot * 8);
      }
      mvn = *(const f32x4*)(mrow + (kc + 1) * 32);   // next-iter mask in flight
      asm volatile("s_waitcnt vmcnt(3)" ::: "memory");  // prev K prefetch retired
    } else {
      asm volatile("s_waitcnt vmcnt(0)" ::: "memory");
    }
    __builtin_amdgcn_sched_barrier(0);
    f32x4 a0 = {0.f, 0.f, 0.f, 0.f};
    __builtin_amdgcn_s_setprio(1);
#pragma unroll
    for (int ks = 0; ks < 8; ks++) {
      int g0 = ((ks * 4 + t) ^ (c & 7)) * 8;
      short8 kf = *(const short8*)(Ksm[cur] + (kh + c) * 256 + g0);
      a0 = __builtin_amdgcn_mfma_f32_16x16x32_bf16(kf, qf[ks], a0, 0, 0, 0);
    }
    __builtin_amdgcn_s_setprio(0);
#pragma unroll
    for (int j = 0; j < 4; j++) lp += __expf(a0[j] * scale + mv[j]);
    mv = mvn;
  }
  lp += __shfl_xor(lp, 16);
  lp += __shfl_xor(lp, 32);
  if (t == 0) red[w][c] = lp;
  __syncthreads();
  float rinv = 1.0f / (red[s][c] + red[4 + s][c]);

  // ---- pass 2: one barrier/iter; PV and attnW-store lag QK by one chunk ----
  float* awB = attnW + (long)bh * 4194304 + (long)(qblk * 64) * 2048;
  const int psw = ((c >> 1) & 3) << 3;   // bank-bijective granule swizzle (c bits [2:1])
  // cooperative attnW store indexing: thread -> (row 0..63, 16B quarter 0..7)
  const int srow = tid >> 3, sqk = tid & 7;
  const int ss2 = srow >> 4, sc2 = srow & 15;
  const int spsw = ((sc2 >> 1) & 3) << 3;
  const unsigned short* pRd = &Pt[0][ss2][0] + sc2 * 32 + ((sqk * 4) ^ spsw);
  const int ptStride = 4 * 16 * 32;   // shorts between Pt[0] and Pt[1]
  float* awRow = awB + (long)srow * 2048 + sqk * 4;
  f32x4 accO[8];
#pragma unroll
  for (int i = 0; i < 8; i++) accO[i] = (f32x4){0.f, 0.f, 0.f, 0.f};

#pragma unroll
  for (int i = 0; i < 2; i++) {
    int slot = i * 512 + tid;
    gload16(Kg + slot * 8, Ksm[0] + slot * 8);
  }
  mv = *(const f32x4*)(mrow);   // prefetch mask for kc=0
  for (int kc = 0; kc < 64; kc++) {
    int cur = kc & 1;
    asm volatile("s_barrier" ::: "memory");
    f32x4 mvn;
    if (kc < 63) {
      const unsigned short* ksrc = Kg + (long)(kc + 1) * 8192;
      const unsigned short* vsrc = Vg + (long)kc * 8192;   // V[kc] consumed NEXT iter
#pragma unroll
      for (int i = 0; i < 2; i++) {
        int slot = i * 512 + tid;
        gload16(ksrc + slot * 8, Ksm[cur ^ 1] + slot * 8);
        gload16(vsrc + slot * 8, Vsm[cur] + slot * 8);
      }
      mvn = *(const f32x4*)(mrow + (kc + 1) * 32);   // next-iter mask in flight
      asm volatile("s_waitcnt vmcnt(5)" ::: "memory");  // prev iter's K+V retired
    } else {
      const unsigned short* vsrc = Vg + (long)kc * 8192;   // V[63]
#pragma unroll
      for (int i = 0; i < 2; i++) {
        int slot = i * 512 + tid;
        gload16(vsrc + slot * 8, Vsm[cur] + slot * 8);
      }
      asm volatile("s_waitcnt vmcnt(2)" ::: "memory");  // K[63] + V[62] retired
    }
    __builtin_amdgcn_sched_barrier(0);
    f32x4 a0 = {0.f, 0.f, 0.f, 0.f};
    __builtin_amdgcn_s_setprio(1);
#pragma unroll
    for (int ks = 0; ks < 8; ks++) {
      int g0 = ((ks * 4 + t) ^ (c & 7)) * 8;
      short8 kf = *(const short8*)(Ksm[cur] + (kh + c) * 256 + g0);
      a0 = __builtin_amdgcn_mfma_f32_16x16x32_bf16(kf, qf[ks], a0, 0, 0, 0);
    }
    __builtin_amdgcn_s_setprio(0);
    f32x4 p;
#pragma unroll
    for (int j = 0; j < 4; j++) p[j] = __expf(a0[j] * scale + mv[j]) * rinv;
    mv = mvn;
    // P[kc] -> bf16 into Pt[cur] (element k stored at k ^ psw)
    uint2v pw;
    pw[0] = packbf(p[0], p[1]); pw[1] = packbf(p[2], p[3]);
    *(uint2v*)(&Pt[cur][s][0] + c * 32 + ((kh + t * 4) ^ psw)) = pw;
    if (kc >= 1) {
      // attnW store of chunk kc-1 from Pt[cur^1]: full 128B lines, coalesced
      uint2v pu = *(const uint2v*)(pRd + (cur ^ 1) * ptStride);
      f32x4 aw;
      aw[0] = bf2f((unsigned short)(pu[0] & 0xffff));
      aw[1] = bf2f((unsigned short)(pu[0] >> 16));
      aw[2] = bf2f((unsigned short)(pu[1] & 0xffff));
      aw[3] = bf2f((unsigned short)(pu[1] >> 16));
      __builtin_nontemporal_store(aw, (f32x4*)(awRow + (kc - 1) * 32));
      // PV(kc-1): A = full-k P row from Pt[cur^1], B = V[kc-1] from Vsm[cur^1]
      short8 pa = *(const short8*)(&Pt[cur ^ 1][s][0] + c * 32 + ((t * 8) ^ psw));
      __builtin_amdgcn_s_setprio(1);
#pragma unroll
      for (int di = 0; di < 8; di++) {
        int d = (8 * h + di) * 16 + c;
        short8 vf = *(const short8*)(Vsm[cur ^ 1] + d * 32 + ((t * 8) ^ psw));
        accO[di] = __builtin_amdgcn_mfma_f32_16x16x32_bf16(pa, vf, accO[di], 0, 0, 0);
      }
      __builtin_amdgcn_s_setprio(0);
    }
    // publish Pt[cur] writes before the next top barrier
    asm volatile("s_waitcnt lgkmcnt(0)" ::: "memory");
  }
  // ---- epilogue: attnW chunk 63 + PV(63) from Pt[1] + Vsm[1] ----
  asm volatile("s_waitcnt vmcnt(0)" ::: "memory");   // V[63] landed
  __builtin_amdgcn_s_barrier();                       // Pt[1] published
  __builtin_amdgcn_sched_barrier(0);
  {
    uint2v pu = *(const uint2v*)(pRd + 1 * ptStride);
    f32x4 aw;
    aw[0] = bf2f((unsigned short)(pu[0] & 0xffff));
    aw[1] = bf2f((unsigned short)(pu[0] >> 16));
    aw[2] = bf2f((unsigned short)(pu[1] & 0xffff));
    aw[3] = bf2f((unsigned short)(pu[1] >> 16));
    __builtin_nontemporal_store(aw, (f32x4*)(awRow + 63 * 32));
    short8 pa = *(const short8*)(&Pt[1][s][0] + c * 32 + ((t * 8) ^ psw));
#pragma unroll
    for (int di = 0; di < 8; di++) {
      int d = (8 * h + di) * 16 + c;
      short8 vf = *(const short8*)(Vsm[1] + d * 32 + ((t * 8) ^ psw));
      accO[di] = __builtin_amdgcn_mfma_f32_16x16x32_bf16(pa, vf, accO[di], 0, 0, 0);
    }
  }
  // attnO epilogue: row = q0 + t*4+j, col = h*128 + di*16 + c (within head)
  long obase = ((long)b * 2048 + q0 + t * 4) * 2048 + (bh & 7) * 256 + h * 128 + c;
#pragma unroll
  for (int di = 0; di < 8; di++)
#pragma unroll
    for (int j = 0; j < 4; j++)
      __builtin_nontemporal_store(f2bf(accO[di][j]),
                                  attnO + obase + (long)j * 2048 + di * 16);
}

extern "C" void kernel_launch(void* const* d_in, const int* in_sizes, int n_in,
                              void* d_out, int out_size, void* d_ws, size_t ws_size,
                              hipStream_t stream) {
  const float* hidden = (const float*)d_in[0];
  const float* mask = (const float*)d_in[1];
  const float* cosb = (const float*)d_in[2];
  const float* sinb = (const float*)d_in[3];
  const float* Wq = (const float*)d_in[4];
  const float* Wk = (const float*)d_in[5];
  const float* Wv = (const float*)d_in[6];
  const float* Wo = (const float*)d_in[7];
  float* out = (float*)d_out;
  float* attnW = out + 8388608;  // attn_weights [2][8][2048][2048] f32

  char* ws = (char*)d_ws;
  unsigned short* hidB  = (unsigned short*)(ws + 0);          // [4096][2048] bf16
  unsigned short* WqkvT = (unsigned short*)(ws + 16777216);   // [2560][2048] bf16
  unsigned short* WoT   = (unsigned short*)(ws + 27262976);   // [2048][2048] bf16
  float*          qkv   = (float*)(ws + 35651584);            // [4096][2560] f32
  unsigned short* Qb    = (unsigned short*)(ws + 77594624);   // [16][2048][256] bf16
  unsigned short* Ksw   = (unsigned short*)(ws + 94371840);   // [2][2048][256] bf16 (swizzled)
  unsigned short* VtC   = (unsigned short*)(ws + 96468992);   // [2][64][256][32] bf16 (blocked)
  unsigned short* attnO = (unsigned short*)(ws + 98566144);   // [4096][2048] bf16

  // 1) hidden -> bf16
  cvt_bf16_kernel<<<4096, 256, 0, stream>>>(hidden, hidB, 8388608L);
  // 2) pack transposed weights (bf16)
  transpose_cvt_kernel<<<dim3(64, 64, 1), dim3(32, 8), 0, stream>>>(Wq, WqkvT, 2048, 2048, 0, 0);
  transpose_cvt_kernel<<<dim3(8, 64, 1), dim3(32, 8), 0, stream>>>(Wk, WqkvT + (long)2048 * 2048, 256, 2048, 0, 0);
  transpose_cvt_kernel<<<dim3(8, 64, 1), dim3(32, 8), 0, stream>>>(Wv, WqkvT + (long)2304 * 2048, 256, 2048, 0, 0);
  transpose_cvt_kernel<<<dim3(64, 64, 1), dim3(32, 8), 0, stream>>>(Wo, WoT, 2048, 2048, 0, 0);
  // 3) QKV projection: [4096][2560] f32
  gemm_bt_kernel<false, false, false><<<dim3(20, 32, 1), 256, 0, stream>>>(
      hidB, WqkvT, qkv, 2048, 2048, 2048, 2560, 0, 0, 0, 0, 0);
  // 4) RoPE -> Q bf16 linear, K bf16 swizzled (cos/sin read once per row)
  rope_kernel<<<4096, 256, 0, stream>>>(qkv, cosb, sinb, Qb, Ksw);
  // 5) V -> blocked transposed bf16
  transpose_v_kernel<<<dim3(8, 64, 2), dim3(32, 8), 0, stream>>>(qkv, VtC);
  // 6) fused attention: attnW (d_out) + attnO  (mask read directly as f32)
  attn_fused_kernel<<<512, 512, 0, stream>>>(Qb, Ksw, VtC, mask, attnW, attnO);
  // 7) output projection -> d_out (non-temporal C store: write-once stream)
  gemm_bt_kernel<false, false, true><<<dim3(16, 32, 1), 256, 0, stream>>>(
      attnO, WoT, out, 2048, 2048, 2048, 2048, 0, 0, 0, 0, 0);
}